// Round 12
// baseline (4834.443 us; speedup 1.0000x reference)
//
#include <hip/hip_runtime.h>
#include <stdint.h>

#define D 512
#define T 2048      // S * var_num = 8 * 256
#define VOCAB 32000
#define NWG 16      // LSTM workgroups

typedef __attribute__((ext_vector_type(8))) short short8;
typedef __attribute__((ext_vector_type(4))) float f32x4;
typedef __attribute__((ext_vector_type(8))) unsigned short u16x8;
typedef __attribute__((ext_vector_type(2))) __fp16 f16x2;   // matches cvt_pkrtz return

__device__ __forceinline__ float fast_rcp(float x) { return __builtin_amdgcn_rcpf(x); }
__device__ __forceinline__ float sigm(float x) { return fast_rcp(1.0f + __expf(-x)); }
__device__ __forceinline__ float tanh_fast(float x) {
  float e = __expf(2.0f * x);
  return 1.0f - 2.0f * fast_rcp(e + 1.0f);  // saturates correctly at +-1, no NaN
}
__device__ __forceinline__ unsigned short f2bf(float f) {  // RTNE float->bf16
  unsigned u = __float_as_uint(f);
  unsigned r = u + 0x7fffu + ((u >> 16) & 1u);
  return (unsigned short)(r >> 16);
}
__device__ __forceinline__ uint64_t AL(const uint64_t* p) {
  return __hip_atomic_load(p, __ATOMIC_RELAXED, __HIP_MEMORY_SCOPE_AGENT);
}
union U32H2 { unsigned u; f16x2 h; };

// ---------------------------------------------------------------------------
// Kernel 1: merged = ctx @ Wm + bm ; xz = merged @ W + b   (per 4-row block)
// ---------------------------------------------------------------------------
__global__ __launch_bounds__(512) void prep_kernel(
    const float* __restrict__ ctx, const float* __restrict__ Wm,
    const float* __restrict__ bm, const float* __restrict__ W,
    const float* __restrict__ b, float* __restrict__ xz)
{
  __shared__ float ctx_s[4][1024];
  __shared__ float mg_s[4][512];
  const int tid = threadIdx.x;
  const int r0 = blockIdx.x * 4;

  for (int i = tid; i < 1024; i += 512) {
    int rr = i >> 8, c4 = (i & 255) * 4;
    *(float4*)&ctx_s[rr][c4] = *(const float4*)&ctx[(size_t)(r0 + rr) * 1024 + c4];
  }
  __syncthreads();
  {
    const int rr = tid >> 7, cg = (tid & 127) * 4;
    float a0 = bm[cg], a1 = bm[cg + 1], a2 = bm[cg + 2], a3 = bm[cg + 3];
    for (int k = 0; k < 1024; k += 4) {
      float4 cv = *(float4*)&ctx_s[rr][k];
      #pragma unroll
      for (int kk = 0; kk < 4; kk++) {
        float cc = (kk == 0) ? cv.x : (kk == 1) ? cv.y : (kk == 2) ? cv.z : cv.w;
        float4 wv = *(const float4*)&Wm[(size_t)(k + kk) * 512 + cg];
        a0 += cc * wv.x; a1 += cc * wv.y; a2 += cc * wv.z; a3 += cc * wv.w;
      }
    }
    *(float4*)&mg_s[rr][cg] = make_float4(a0, a1, a2, a3);
  }
  __syncthreads();
  {
    const int rr = tid >> 7, cg = (tid & 127) * 16;
    float acc[16];
    #pragma unroll
    for (int c = 0; c < 16; c++) acc[c] = b[cg + c];
    for (int k = 0; k < 512; k += 4) {
      float4 mv = *(float4*)&mg_s[rr][k];
      #pragma unroll
      for (int kk = 0; kk < 4; kk++) {
        float cc = (kk == 0) ? mv.x : (kk == 1) ? mv.y : (kk == 2) ? mv.z : mv.w;
        #pragma unroll
        for (int c4 = 0; c4 < 4; c4++) {
          float4 wv = *(const float4*)&W[(size_t)(k + kk) * 2048 + cg + c4 * 4];
          acc[c4 * 4 + 0] += cc * wv.x; acc[c4 * 4 + 1] += cc * wv.y;
          acc[c4 * 4 + 2] += cc * wv.z; acc[c4 * 4 + 3] += cc * wv.w;
        }
      }
    }
    #pragma unroll
    for (int c4 = 0; c4 < 4; c4++)
      *(float4*)&xz[(size_t)(r0 + rr) * 2048 + cg + c4 * 4] =
          make_float4(acc[c4 * 4], acc[c4 * 4 + 1], acc[c4 * 4 + 2], acc[c4 * 4 + 3]);
  }
}

// ---------------------------------------------------------------------------
// Kernel 2: Wlt[c][k] = bf16(Wl[k][c])
// ---------------------------------------------------------------------------
__global__ __launch_bounds__(256) void wl_convert_kernel(
    const float* __restrict__ Wl, unsigned short* __restrict__ Wlt)
{
  const int c = blockIdx.x * 256 + threadIdx.x;
  for (int k8 = 0; k8 < 64; k8++) {
    u16x8 v;
    #pragma unroll
    for (int e = 0; e < 8; e++)
      v[e] = f2bf(Wl[(size_t)(k8 * 8 + e) * VOCAB + c]);
    *(u16x8*)&Wlt[(size_t)c * 512 + k8 * 8] = v;
  }
}

// ---------------------------------------------------------------------------
// Kernel 2b: packed-f16 U for the 4-compute-wave lstm mapping.
// lstm compute thread (wg, tid<256): g=tid>>4, l=tid&15, u0=wg*32+g*2,
// cols col(c)=(c>>1)*512 + u0 + (c&1), c=0..7; row pairs (l+16ep, l+16ep+256),
// ep=0..15. Upr[((wg*256+tid)*16 + ep)*8 + c] = pack(U[r][col], U[r+256][col]).
// Per lstm thread: 128 contiguous u32 = 512B = 32 dwordx4.
// ---------------------------------------------------------------------------
__global__ __launch_bounds__(256) void uconv3_kernel(
    const float* __restrict__ U, unsigned* __restrict__ Upr)
{
  const int wg = blockIdx.x;            // 0..15
  const int tid = threadIdx.x;          // 0..255
  const int g = tid >> 4, l = tid & 15;
  const int u0 = wg * 32 + g * 2;
  unsigned* dst = Upr + ((size_t)(wg * 256 + tid)) * 128;
  for (int ep = 0; ep < 16; ep++) {
    const int r = l + 16 * ep;
    unsigned outv[8];
    #pragma unroll
    for (int c = 0; c < 8; c++) {
      const int col = (c >> 1) * 512 + u0 + (c & 1);
      U32H2 w;
      w.h[0] = (__fp16)U[(size_t)r * 2048 + col];
      w.h[1] = (__fp16)U[(size_t)(r + 256) * 2048 + col];
      outv[c] = w.u;
    }
    *(uint4*)(dst + ep * 8)     = make_uint4(outv[0], outv[1], outv[2], outv[3]);
    *(uint4*)(dst + ep * 8 + 4) = make_uint4(outv[4], outv[5], outv[6], outv[7]);
  }
}

// ---------------------------------------------------------------------------
// Kernel 3: sequential LSTM, 16 WGs x 512 (cooperative), WAVE-SPECIALIZED:
//   waves 0-3 (tid<256): compute. 16 groups x 16 lanes; group g owns units
//     u0=wg*32+g*2, u0+1 (4 gates); lane l: rows {l+16ep, l+16ep+256} x 8 cols
//     packed-f16 (u2[16][8], 128 VGPR; all of U register-resident grid-wide).
//   waves 4-7 (tid>=256): pollers. Thread pt=tid-256 polls 2 tagged u64 words,
//     writes h_lds[(t+1)&1]. Polls are IN FLIGHT while compute runs -> the
//     store->detect path is ~1 MALL RTT, not (compute + drain + poll-restart)
//     as in R9/R11 (2.06us/step, 5 structures converged there).
// ONE barrier/step. Exchange semantics identical to R9 (agent-scope relaxed
// atomics, tagged u64, parity double-buffer) - only the schedule changed.
// ---------------------------------------------------------------------------
__global__
__attribute__((amdgpu_flat_work_group_size(512, 512)))
__attribute__((amdgpu_waves_per_eu(2, 2)))
void lstm_kernel(
    const float* __restrict__ xz, const unsigned* __restrict__ Upr,
    uint64_t* __restrict__ hb, unsigned short* __restrict__ hs)
{
  __shared__ float h_lds[2][512];
  const int tid = threadIdx.x;
  const int wg = blockIdx.x;
  const bool is_comp = (tid < 256);

  h_lds[0][tid] = 0.0f;   // h_0 = 0 (blockDim 512 covers [0,512))

  // compute-side state
  const int g = tid >> 4, l = tid & 15;
  const int lane = tid & 63;
  const int u0 = wg * 32 + g * 2;
  const bool gl = is_comp && (l < 2);   // gate lane: unit u0+l
  const int b0 = l & 1, b1 = (l >> 1) & 1, b2v = (l >> 2) & 1;

  unsigned u2[16][8];
  float xv0 = 0.f, xv1 = 0.f, xv2 = 0.f, xv3 = 0.f;
  if (is_comp) {
    // one-time exactly-once U load: 32 contiguous dwordx4 (volatile asm:
    // cannot be rematerialized; waves_per_eu(2) budget 256 VGPR -> resident)
    const unsigned* ubase = Upr + ((size_t)(wg * 256 + tid)) * 128;
    uint4 uv[32];
    #pragma unroll
    for (int i = 0; i < 16; i++) {
      const unsigned* ap = ubase + i * 8;
      asm volatile("global_load_dwordx4 %0, %1, off"
                   : "=v"(uv[i * 2]) : "v"(ap));
      asm volatile("global_load_dwordx4 %0, %1, off offset:16"
                   : "=v"(uv[i * 2 + 1]) : "v"(ap));
    }
    asm volatile("s_waitcnt vmcnt(0)" ::: "memory");
    #pragma unroll
    for (int ep = 0; ep < 16; ep++) {
      uint4 a = uv[ep * 2], b4 = uv[ep * 2 + 1];
      u2[ep][0] = a.x; u2[ep][1] = a.y; u2[ep][2] = a.z; u2[ep][3] = a.w;
      u2[ep][4] = b4.x; u2[ep][5] = b4.y; u2[ep][6] = b4.z; u2[ep][7] = b4.w;
    }
    if (gl) {  // xz for t=0
      const float* xp = &xz[(size_t)0 * 2048 + u0 + l];
      xv0 = xp[0]; xv1 = xp[512]; xv2 = xp[1024]; xv3 = xp[1536];
    }
  }
  float creg = 0.0f;
  __syncthreads();  // h_lds[0] init complete

  for (int t = 0; t < T; t++) {
    if (is_comp) {
      #pragma unroll
      for (int ep = 0; ep < 16; ep++) {
        #pragma unroll
        for (int c = 0; c < 8; c++) asm volatile("" : "+v"(u2[ep][c]));  // pin
      }
      const int par = t & 1;
      // matvec: 16 row-pairs x 8 cols, packed-f16 dot2
      float zp[8];
      #pragma unroll
      for (int c = 0; c < 8; c++) zp[c] = 0.0f;
      #pragma unroll
      for (int ep = 0; ep < 16; ep++) {
        float hlo = h_lds[par][l + 16 * ep];
        float hhi = h_lds[par][l + 16 * ep + 256];
        f16x2 h2 = __builtin_amdgcn_cvt_pkrtz(hlo, hhi);
        #pragma unroll
        for (int c = 0; c < 8; c++) {
          U32H2 w; w.u = u2[ep][c];
          zp[c] = __builtin_amdgcn_fdot2(h2, w.h, zp[c], false);
        }
      }
      // 16-lane split-butterfly reduce: 3 halving levels + 1 full + 3 redist
      float q[4];
      #pragma unroll
      for (int j = 0; j < 4; j++) {
        float send = b0 ? zp[2 * j] : zp[2 * j + 1];
        float recv = __shfl_xor(send, 1, 64);
        q[j] = (b0 ? zp[2 * j + 1] : zp[2 * j]) + recv;
      }
      float r2[2];
      #pragma unroll
      for (int j = 0; j < 2; j++) {
        float send = b1 ? q[2 * j] : q[2 * j + 1];
        float recv = __shfl_xor(send, 2, 64);
        r2[j] = (b1 ? q[2 * j + 1] : q[2 * j]) + recv;
      }
      float z;
      {
        float send = b2v ? r2[0] : r2[1];
        float recv = __shfl_xor(send, 4, 64);
        z = (b2v ? r2[1] : r2[0]) + recv;
      }
      z += __shfl_xor(z, 8, 64);   // full 16-lane sum; lane holds col (l&7)
      float zf = __shfl(z, (lane & 48) + 2 + b0, 64);
      float zg = __shfl(z, (lane & 48) + 4 + b0, 64);
      float zo = __shfl(z, (lane & 48) + 6 + b0, 64);

      if (gl) {  // gates for unit u0+l
        float ig = sigm(z + xv0);
        float fg = sigm(zf + xv1);
        float gg = tanh_fast(zg + xv2);
        float og = sigm(zo + xv3);
        creg = fg * creg + ig * gg;
        float h = og * tanh_fast(creg);
        uint64_t pk = ((uint64_t)(unsigned)(t + 1) << 32) | (uint64_t)__float_as_uint(h);
        __hip_atomic_store(&hb[((size_t)((t + 1) & 1) << 9) + u0 + l], pk,
                           __ATOMIC_RELAXED, __HIP_MEMORY_SCOPE_AGENT);
        hs[(size_t)t * 512 + u0 + l] = f2bf(h);
        // prefetch xz for t+1 (completes during pollers' detection window)
        const float* xp = &xz[(size_t)((t + 1) & 255) * 2048 + u0 + l];
        xv0 = xp[0]; xv1 = xp[512]; xv2 = xp[1024]; xv3 = xp[1536];
      }
    } else {
      // poller: detect h_{t+1} (2 words), write h_lds[(t+1)&1]
      const int pt = tid - 256;
      uint64_t* hw = hb + ((size_t)((t + 1) & 1) << 9) + pt * 2;
      const unsigned tt = (unsigned)(t + 1);
      uint64_t w0, w1;
      for (;;) {
        w0 = AL(hw); w1 = AL(hw + 1);
        if (((unsigned)(w0 >> 32) == tt) & ((unsigned)(w1 >> 32) == tt)) break;
      }
      h_lds[(t + 1) & 1][pt * 2]     = __uint_as_float((unsigned)w0);
      h_lds[(t + 1) & 1][pt * 2 + 1] = __uint_as_float((unsigned)w1);
    }
    __syncthreads();  // h_lds[(t+1)&1] complete; stores drained under poll wait
  }
}

// ---------------------------------------------------------------------------
// Kernel 4: logits = hs @ Wl + bl. 8-wave 128(M)x256(N) tile, K-step 32,
// bf16 MFMA 16x16x32. Output remap: gemm row t -> out row (t%256)*8 + t/256.
// ---------------------------------------------------------------------------
__global__ __launch_bounds__(512) void logits_kernel(
    const unsigned short* __restrict__ hs, const unsigned short* __restrict__ Wlt,
    const float* __restrict__ bl, float* __restrict__ out)
{
  __shared__ unsigned short As[128][40];  // [row][k] +8 pad
  __shared__ unsigned short Bs[256][40];  // [col][k] +8 pad
  const int tid = threadIdx.x;
  const int bx = blockIdx.x, by = blockIdx.y;
  const int lane = tid & 63, w = tid >> 6;
  const int wr = w >> 2, wc = w & 3;

  f32x4 acc[4][4];
  #pragma unroll
  for (int i = 0; i < 4; i++) {
    #pragma unroll
    for (int j = 0; j < 4; j++) acc[i][j] = (f32x4){0.0f, 0.0f, 0.0f, 0.0f};
  }

  for (int kk = 0; kk < 512; kk += 32) {
    {  // A: 128 rows x 32 k = 512 chunks of 16B, 1/thread
      int r = tid >> 2, c8 = (tid & 3) * 8;
      *(uint4*)&As[r][c8] = *(const uint4*)&hs[(size_t)(by * 128 + r) * 512 + kk + c8];
    }
    #pragma unroll
    for (int i = 0; i < 2; i++) {  // B: 256 rows x 32 k = 1024 chunks, 2/thread
      int chunk = tid * 2 + i;
      int r = chunk >> 2, c8 = (chunk & 3) * 8;
      *(uint4*)&Bs[r][c8] = *(const uint4*)&Wlt[(size_t)(bx * 256 + r) * 512 + kk + c8];
    }
    __syncthreads();
    short8 af[4], bf[4];
    #pragma unroll
    for (int fr = 0; fr < 4; fr++)
      af[fr] = *(const short8*)&As[wr * 64 + fr * 16 + (lane & 15)][(lane >> 4) * 8];
    #pragma unroll
    for (int fc = 0; fc < 4; fc++)
      bf[fc] = *(const short8*)&Bs[wc * 64 + fc * 16 + (lane & 15)][(lane >> 4) * 8];
    #pragma unroll
    for (int fr = 0; fr < 4; fr++) {
      #pragma unroll
      for (int fc = 0; fc < 4; fc++)
        acc[fr][fc] = __builtin_amdgcn_mfma_f32_16x16x32_bf16(af[fr], bf[fc], acc[fr][fc], 0, 0, 0);
    }
    __syncthreads();
  }

  #pragma unroll
  for (int fc = 0; fc < 4; fc++) {
    int col = bx * 256 + wc * 64 + fc * 16 + (lane & 15);
    float blv = bl[col];
    #pragma unroll
    for (int fr = 0; fr < 4; fr++) {
      int row0 = by * 128 + wr * 64 + fr * 16 + (lane >> 4) * 4;
      #pragma unroll
      for (int j = 0; j < 4; j++) {
        int row = row0 + j;
        int orow = (row & 255) * 8 + (row >> 8);
        out[(size_t)orow * VOCAB + col] = acc[fr][fc][j] + blv;
      }
    }
  }
}

// ---------------------------------------------------------------------------
extern "C" void kernel_launch(void* const* d_in, const int* in_sizes, int n_in,
                              void* d_out, int out_size, void* d_ws, size_t ws_size,
                              hipStream_t stream)
{
  const float* ctx = (const float*)d_in[0];
  const float* Wm  = (const float*)d_in[1];
  const float* bm  = (const float*)d_in[2];
  const float* W   = (const float*)d_in[3];
  const float* U   = (const float*)d_in[4];
  const float* b   = (const float*)d_in[5];
  const float* Wl  = (const float*)d_in[6];
  const float* bl  = (const float*)d_in[7];
  float* out = (float*)d_out;

  char* ws = (char*)d_ws;
  uint64_t* hb        = (uint64_t*)ws;                                   // 8 KB (2x512 u64)
  float* xz           = (float*)(ws + 65536);                            // 2 MB
  unsigned short* hs  = (unsigned short*)(ws + 65536 + (1 << 21));       // 2 MB
  unsigned* Upr       = (unsigned*)(ws + 65536 + (2 << 21));             // 2 MB
  unsigned short* Wlt = (unsigned short*)(ws + 65536 + (3 << 21));       // 32.77 MB

  hipMemsetAsync(hb, 0, 8192, stream);  // tags = 0 (benign; pollers seek t+1>=1)
  prep_kernel<<<dim3(64), dim3(512), 0, stream>>>(ctx, Wm, bm, W, b, xz);
  uconv3_kernel<<<dim3(16), dim3(256), 0, stream>>>(U, Upr);
  wl_convert_kernel<<<dim3(125), dim3(256), 0, stream>>>(Wl, Wlt);

  void* args[] = { (void*)&xz, (void*)&Upr, (void*)&hb, (void*)&hs };
  hipLaunchCooperativeKernel((void*)lstm_kernel, dim3(NWG), dim3(512), args, 0, stream);

  logits_kernel<<<dim3(125, 16), dim3(512), 0, stream>>>(hs, Wlt, bl, out);
}